// Round 10
// baseline (525.947 us; speedup 1.0000x reference)
//
#include <hip/hip_runtime.h>
#include <hip/hip_bf16.h>
#include <cstdint>
#include <cstddef>

#define D 256
#define NTOK 65536
#define KCODES 4096
#define Q_ELEMS (NTOK * D)   // 16777216
#define DELTA 3.0e-4f
#define CAP 16

typedef short bf16x8 __attribute__((ext_vector_type(8)));
typedef float f32x4 __attribute__((ext_vector_type(4)));
typedef unsigned short ushort8 __attribute__((ext_vector_type(8)));

__device__ __forceinline__ void gload_lds16(const float* g, float* l) {
  __builtin_amdgcn_global_load_lds(
      (const __attribute__((address_space(1))) void*)(g),
      (__attribute__((address_space(3))) void*)(l), 16, 0, 0);
}
__device__ __forceinline__ unsigned short f2bf(float f) {
  __hip_bfloat16 h = __float2bfloat16(f);
  unsigned short u;
  __builtin_memcpy(&u, &h, 2);
  return u;
}
__device__ __forceinline__ float bf2f(unsigned short u) {
  __hip_bfloat16 h;
  __builtin_memcpy(&h, &u, 2);
  return __bfloat162float(h);
}

// ---------------- kernel 1a: codebook squared norms (f64 -> f32) ----------
__global__ __launch_bounds__(256) void ee_kernel(const float* __restrict__ cb,
                                                 float* __restrict__ se) {
  const int row = blockIdx.x * 4 + (threadIdx.x >> 6);
  const int lane = threadIdx.x & 63;
  const float4 v = reinterpret_cast<const float4*>(cb + (size_t)row * D)[lane];
  double s = (double)v.x * v.x + (double)v.y * v.y +
             (double)v.z * v.z + (double)v.w * v.w;
#pragma unroll
  for (int o = 32; o > 0; o >>= 1) s += __shfl_down(s, o, 64);
  if (lane == 0) se[row] = (float)s;
}

// ---------------- kernel 1b: token squared norms (f64 -> f32) -------------
__global__ __launch_bounds__(256) void xx_kernel(const float* __restrict__ x,
                                                 float* __restrict__ sx) {
  const int row = blockIdx.x * 4 + (threadIdx.x >> 6);
  const int lane = threadIdx.x & 63;
  const float4 v = reinterpret_cast<const float4*>(x + (size_t)row * D)[lane];
  double s = (double)v.x * v.x + (double)v.y * v.y +
             (double)v.z * v.z + (double)v.w * v.w;
#pragma unroll
  for (int o = 32; o > 0; o >>= 1) s += __shfl_down(s, o, 64);
  if (lane == 0) sx[row] = (float)s;
}

// ---------------- kernel 1c: pack codebook e_hi -> LDS-image bf16 tiles ---
__global__ __launch_bounds__(256) void pack_e_kernel(const float* __restrict__ cb,
                                                     unsigned short* __restrict__ bpack) {
  const int gid = blockIdx.x * 256 + threadIdx.x;  // 16384 = 4096 codes x 4 kt
  const int c = gid >> 2;
  const int kt = gid & 3;
  const int row = c & 127;
  const int swz = (row & 7) << 3;
  unsigned short* dst = bpack + ((size_t)((c >> 7) * 4 + kt)) * 8192 + row * 64;
  const float* src = cb + (size_t)c * D + kt * 64;
#pragma unroll
  for (int j = 0; j < 8; ++j) {
    ushort8 o;
#pragma unroll
    for (int e = 0; e < 8; ++e) o[e] = f2bf(src[j * 8 + e]);
    *reinterpret_cast<ushort8*>(dst + ((j * 8) ^ swz)) = o;
  }
}

// ---------------- kernel 2: MFMA screening v4 (3 blocks/CU) ---------------
// 256 thr / 4 waves / 128 tokens per block; 512 blocks. Ring-2 bbuf
// (stage u+1 into the slot freed at the end of u-1 while computing u) cuts
// LDS to 48.5KB -> 3 blocks/CU = 12 waves/CU: when one block sits in its
// barrier drain the other two keep the MFMA/LDS pipes busy (m97/m114
// overlap — r9's 2 blocks/CU left all pipes at ~25%). s_setprio(1) wraps
// the MFMA cluster (T5: independent blocks at different phases). Inner
// math identical to r8/r9 (both passed absmax 0): d~ = se - 2*bf16(x).e_hi
// via mfma 16x16x32; candidates (bf16(score)<<16)|idx inserted when
// s <= running_min + DELTA. Capture bound: winner <= rm_final + 1.74e-4
// (8sigma bf16 dot err + ref f32-rounding window) + 6e-5 bf16 store err
// < DELTA = 3e-4.
__global__ __launch_bounds__(256, 3) void screen4_kernel(
    const float* __restrict__ x, const unsigned short* __restrict__ bpack,
    const float* __restrict__ se, unsigned int* __restrict__ ccnt_g,
    unsigned int* __restrict__ cand_g, float* __restrict__ rm_g) {
  __shared__ __attribute__((aligned(16))) unsigned short bbuf[2][8192];  // 32KB
  __shared__ __attribute__((aligned(16))) unsigned short se_lds[KCODES]; // 8KB
  __shared__ unsigned int cand[128][CAP];                                // 8KB
  __shared__ unsigned int ccnt[128];                                     // 0.5KB

  const int tid = threadIdx.x;
  const int lane = tid & 63;
  const int w = tid >> 6;    // 0..3
  const int l15 = lane & 15;
  const int kg = lane >> 4;  // 0..3
  const int tok0 = blockIdx.x * 128;

  if (tid < 128) ccnt[tid] = 0;
  {  // se -> bf16 LDS: each thread converts 16 values
    const float4* s4 = reinterpret_cast<const float4*>(se) + tid * 4;
    const float4 a = s4[0], b = s4[1], c = s4[2], d = s4[3];
    ushort8 o0, o1;
    o0[0] = f2bf(a.x); o0[1] = f2bf(a.y); o0[2] = f2bf(a.z); o0[3] = f2bf(a.w);
    o0[4] = f2bf(b.x); o0[5] = f2bf(b.y); o0[6] = f2bf(b.z); o0[7] = f2bf(b.w);
    o1[0] = f2bf(c.x); o1[1] = f2bf(c.y); o1[2] = f2bf(c.z); o1[3] = f2bf(c.w);
    o1[4] = f2bf(d.x); o1[5] = f2bf(d.y); o1[6] = f2bf(d.z); o1[7] = f2bf(d.w);
    *reinterpret_cast<ushort8*>(&se_lds[tid * 16]) = o0;
    *reinterpret_cast<ushort8*>(&se_lds[tid * 16 + 8]) = o1;
  }

  // A fragments (hi-only bf16): 2 row-groups x 8 ksteps, static indices
  bf16x8 ah[2][8];
#pragma unroll
  for (int gi = 0; gi < 2; ++gi) {
    const int t = tok0 + w * 32 + gi * 16 + l15;
    const float* xp = x + (size_t)t * D;
#pragma unroll
    for (int ks = 0; ks < 8; ++ks) {
      const float4 v0 = *reinterpret_cast<const float4*>(xp + ks * 32 + kg * 8);
      const float4 v1 = *reinterpret_cast<const float4*>(xp + ks * 32 + kg * 8 + 4);
      const float xv[8] = {v0.x, v0.y, v0.z, v0.w, v1.x, v1.y, v1.z, v1.w};
      bf16x8 h;
#pragma unroll
      for (int e = 0; e < 8; ++e) h[e] = (short)f2bf(xv[e]);
      ah[gi][ks] = h;
    }
  }

  // stage one 16KB unit: 4 waves x 4 chunks x (64 lanes x 16B)
  auto STAGE = [&](int u) {
    const char* s = (const char*)bpack + (size_t)u * 16384 + w * 4096 + lane * 16;
    char* d = (char*)&bbuf[u & 1][0] + w * 4096;
    gload_lds16((const float*)s, (float*)d);
    gload_lds16((const float*)(s + 1024), (float*)(d + 1024));
    gload_lds16((const float*)(s + 2048), (float*)(d + 2048));
    gload_lds16((const float*)(s + 3072), (float*)(d + 3072));
  };

  float rm[2][4];
#pragma unroll
  for (int fr = 0; fr < 2; ++fr)
#pragma unroll
    for (int q = 0; q < 4; ++q) rm[fr][q] = 3.4e38f;

  f32x4 acc[2][8];

  STAGE(0);
  __syncthreads();  // unit 0 resident; se/ccnt ready

  for (int ct4 = 0; ct4 < 32; ++ct4) {
#pragma unroll
    for (int kt = 0; kt < 4; ++kt) {  // kt compile-time: ah[] stays in VGPRs
      const int u = ct4 * 4 + kt;
      if (u + 1 < 128) STAGE(u + 1);  // into slot freed at end of u-1
      if (kt == 0) {
#pragma unroll
        for (int fr = 0; fr < 2; ++fr)
#pragma unroll
          for (int fc = 0; fc < 8; ++fc) acc[fr][fc] = (f32x4){0.f, 0.f, 0.f, 0.f};
      }
      const unsigned short* bb = &bbuf[u & 1][0];
      __builtin_amdgcn_s_setprio(1);
#pragma unroll
      for (int kh = 0; kh < 2; ++kh) {
        const int ks = kt * 2 + kh;  // compile-time
        bf16x8 bfrag[8];
#pragma unroll
        for (int fc = 0; fc < 8; ++fc) {
          const int row = fc * 16 + l15;
          const int off = row * 64 + ((kh * 32 + kg * 8) ^ ((row & 7) << 3));
          bfrag[fc] = *reinterpret_cast<const bf16x8*>(bb + off);
        }
#pragma unroll
        for (int fr = 0; fr < 2; ++fr)
#pragma unroll
          for (int fc = 0; fc < 8; ++fc)
            acc[fr][fc] = __builtin_amdgcn_mfma_f32_16x16x32_bf16(
                ah[fr][ks], bfrag[fc], acc[fr][fc], 0, 0, 0);
      }
      __builtin_amdgcn_s_setprio(0);
      if (kt == 3) {  // code-tile ct4 finished: mins + candidate inserts
        float sef[8];
#pragma unroll
        for (int fc = 0; fc < 8; ++fc)
          sef[fc] = bf2f(se_lds[ct4 * 128 + fc * 16 + l15]);
#pragma unroll
        for (int fr = 0; fr < 2; ++fr)
#pragma unroll
          for (int q = 0; q < 4; ++q) {
            float m = fmaf(-2.0f, acc[fr][0][q], sef[0]);
#pragma unroll
            for (int fc = 1; fc < 8; ++fc)
              m = fminf(m, fmaf(-2.0f, acc[fr][fc][q], sef[fc]));
            m = fminf(m, __shfl_xor(m, 1, 64));
            m = fminf(m, __shfl_xor(m, 2, 64));
            m = fminf(m, __shfl_xor(m, 4, 64));
            m = fminf(m, __shfl_xor(m, 8, 64));
            rm[fr][q] = fminf(rm[fr][q], m);
            const float thr = rm[fr][q] + DELTA;
            const int tl = w * 32 + fr * 16 + kg * 4 + q;
#pragma unroll
            for (int fc = 0; fc < 8; ++fc) {
              const float s = fmaf(-2.0f, acc[fr][fc][q], sef[fc]);
              if (s <= thr) {
                const unsigned p = atomicAdd(&ccnt[tl], 1u);
                if (p < CAP)
                  cand[tl][p] = ((unsigned)f2bf(s) << 16) |
                                (unsigned)(ct4 * 128 + fc * 16 + l15);
              }
            }
          }
      }
      __syncthreads();  // unit u fully consumed; u+1 resident
    }
  }

  if (tid < 128) ccnt_g[tok0 + tid] = ccnt[tid];
  if (l15 == 0) {
#pragma unroll
    for (int fr = 0; fr < 2; ++fr)
#pragma unroll
      for (int q = 0; q < 4; ++q)
        rm_g[tok0 + w * 32 + fr * 16 + kg * 4 + q] = rm[fr][q];
  }
  for (int j = tid; j < 128 * CAP; j += 256)
    cand_g[(size_t)tok0 * CAP + j] = cand[j >> 4][j & 15];
}

// ---------------- kernel 3: exact-chain rescore (filtered, r8 shape) ------
// One thread per token. Filter candidates by unpacked bf16 score <= rm+DELTA,
// then replicate reference f32 semantics bit-for-bit on the ~1-2 survivors:
// sequential fmaf chain d=0..255, dist = fl(fl(sx+se)-2*dot), lex-min.
__global__ __launch_bounds__(256) void rescore_kernel(
    const float* __restrict__ x, const float* __restrict__ cb,
    const float* __restrict__ se, const float* __restrict__ sx,
    const unsigned int* __restrict__ ccnt_g, const unsigned int* __restrict__ cand_g,
    const float* __restrict__ rm_g, int* __restrict__ idx_i,
    float* __restrict__ idxf_out, unsigned int* __restrict__ ovf_count,
    int* __restrict__ ovf_list) {
  const int t = blockIdx.x * 256 + threadIdx.x;
  const unsigned n = ccnt_g[t];
  if (n > CAP) {  // list overflowed: defer to full-scan fallback
    const unsigned p = atomicAdd(ovf_count, 1u);
    ovf_list[p] = t;
    return;
  }
  const float thr = rm_g[t] + DELTA;
  const float sxv = sx[t];
  const float4* xp = reinterpret_cast<const float4*>(x + (size_t)t * D);
  float bq = 3.4e38f;
  int bc = 0x7fffffff;
  for (unsigned k = 0; k < n; ++k) {
    const unsigned pk = cand_g[(size_t)t * CAP + k];
    if (bf2f((unsigned short)(pk >> 16)) > thr) continue;
    const int c = (int)(pk & 0xFFFFu);
    const float4* cp = reinterpret_cast<const float4*>(cb + (size_t)c * D);
    float acc = 0.0f;
#pragma unroll 8
    for (int d4 = 0; d4 < 64; ++d4) {
      const float4 xv = xp[d4];
      const float4 ev = cp[d4];
      acc = fmaf(xv.x, ev.x, acc);
      acc = fmaf(xv.y, ev.y, acc);
      acc = fmaf(xv.z, ev.z, acc);
      acc = fmaf(xv.w, ev.w, acc);
    }
    const float r = sxv + se[c];
    const float q = r - 2.0f * acc;
    if (q < bq || (q == bq && c < bc)) { bq = q; bc = c; }
  }
  idx_i[t] = bc;
  idxf_out[t] = (float)bc;
}

// ---------------- kernel 3b: full-scan fallback for overflowed tokens -----
__global__ __launch_bounds__(256) void ovf_kernel(
    const float* __restrict__ x, const float* __restrict__ cb,
    const float* __restrict__ se, const float* __restrict__ sx,
    const unsigned int* __restrict__ ovf_count, const int* __restrict__ ovf_list,
    int* __restrict__ idx_i, float* __restrict__ idxf_out) {
  __shared__ float bvv[256];
  __shared__ int bii[256];
  const int tid = threadIdx.x;
  const unsigned cnt = *ovf_count;
  for (unsigned i = blockIdx.x; i < cnt; i += gridDim.x) {
    const int t = ovf_list[i];
    const float sxv = sx[t];
    const float4* xp = reinterpret_cast<const float4*>(x + (size_t)t * D);
    float bq = 3.4e38f;
    int bc = 0x7fffffff;
    for (int c = tid; c < KCODES; c += 256) {
      const float4* cp = reinterpret_cast<const float4*>(cb + (size_t)c * D);
      float acc = 0.0f;
#pragma unroll 8
      for (int d4 = 0; d4 < 64; ++d4) {
        const float4 xv = xp[d4];
        const float4 ev = cp[d4];
        acc = fmaf(xv.x, ev.x, acc);
        acc = fmaf(xv.y, ev.y, acc);
        acc = fmaf(xv.z, ev.z, acc);
        acc = fmaf(xv.w, ev.w, acc);
      }
      const float r = sxv + se[c];
      const float q = r - 2.0f * acc;
      if (q < bq || (q == bq && c < bc)) { bq = q; bc = c; }
    }
    bvv[tid] = bq;
    bii[tid] = bc;
    __syncthreads();
    for (int o = 128; o > 0; o >>= 1) {
      if (tid < o) {
        const float v2 = bvv[tid + o];
        const int c2 = bii[tid + o];
        if (v2 < bvv[tid] || (v2 == bvv[tid] && c2 < bii[tid])) {
          bvv[tid] = v2;
          bii[tid] = c2;
        }
      }
      __syncthreads();
    }
    if (tid == 0) {
      idx_i[t] = bii[0];
      idxf_out[t] = (float)bii[0];
    }
    __syncthreads();
  }
}

// ---------------- fallback argmin (tiny-ws path; round-4 kernel) ----------
__global__ __launch_bounds__(256) void argmin_fb_kernel(const float* __restrict__ x,
                                                        const float* __restrict__ cb,
                                                        const float* __restrict__ se,
                                                        const float* __restrict__ sx,
                                                        int* __restrict__ idx_out,
                                                        float* __restrict__ idxf_out) {
  __shared__ __attribute__((aligned(16))) float xs[64 * 128];
  __shared__ __attribute__((aligned(16))) float es[64 * 128];
  const int tid = threadIdx.x;
  const int lane = tid & 63;
  const int w = tid >> 6;
  const int wt = w & 1;
  const int wc = w >> 1;
  const int tgl = lane & 7;
  const int cgl = lane >> 3;
  const int t0 = wt * 64 + tgl * 8;
  const int c0 = wc * 64 + cgl * 8;
  const int tok0 = blockIdx.x * 128;
  float sxf[8];
#pragma unroll
  for (int i = 0; i < 8; ++i) sxf[i] = sx[tok0 + t0 + i];
  float bv[8];
  int bi[8];
#pragma unroll
  for (int i = 0; i < 8; ++i) { bv[i] = 3.4e38f; bi[i] = 0; }
  for (int ct = 0; ct < KCODES / 128; ++ct) {
    float acc[8][8] = {};
    for (int kt = 0; kt < 4; ++kt) {
      __syncthreads();
      {
        const float* xsrc = x + (size_t)tok0 * D + kt * 64;
        const float* esrc = cb + (size_t)(ct * 128) * D + kt * 64;
#pragma unroll
        for (int p = 0; p < 8; ++p) {
          const int idx = p * 256 + tid;
          const int t = idx >> 4;
          const int c = idx & 15;
          const int colp = (t + 8 * (c >> 1)) & 127;
          const float4 xv = *reinterpret_cast<const float4*>(xsrc + (size_t)t * D + c * 4);
          float* xd = &xs[(c * 4) * 128 + colp];
          xd[0] = xv.x; xd[128] = xv.y; xd[256] = xv.z; xd[384] = xv.w;
          const float4 ev = *reinterpret_cast<const float4*>(esrc + (size_t)t * D + c * 4);
          float* ed = &es[(c * 4) * 128 + colp];
          ed[0] = ev.x; ed[128] = ev.y; ed[256] = ev.z; ed[384] = ev.w;
        }
      }
      __syncthreads();
      for (int kp = 0; kp < 8; ++kp) {
        const float* xb = &xs[(kp * 8) * 128 + ((t0 + 8 * kp) & 127)];
        const float* eb = &es[(kp * 8) * 128 + ((c0 + 8 * kp) & 127)];
#pragma unroll
        for (int k2 = 0; k2 < 8; ++k2) {
          const float4 xv0 = *reinterpret_cast<const float4*>(xb + k2 * 128);
          const float4 xv1 = *reinterpret_cast<const float4*>(xb + k2 * 128 + 4);
          const float4 ev0 = *reinterpret_cast<const float4*>(eb + k2 * 128);
          const float4 ev1 = *reinterpret_cast<const float4*>(eb + k2 * 128 + 4);
          const float xa[8] = {xv0.x, xv0.y, xv0.z, xv0.w, xv1.x, xv1.y, xv1.z, xv1.w};
          const float ea[8] = {ev0.x, ev0.y, ev0.z, ev0.w, ev1.x, ev1.y, ev1.z, ev1.w};
#pragma unroll
          for (int i = 0; i < 8; ++i)
#pragma unroll
            for (int j = 0; j < 8; ++j) acc[i][j] = fmaf(xa[i], ea[j], acc[i][j]);
        }
      }
    }
#pragma unroll
    for (int j = 0; j < 8; ++j) {
      const int cidx = ct * 128 + c0 + j;
      const float sef = se[cidx];
#pragma unroll
      for (int i = 0; i < 8; ++i) {
        const float r = sxf[i] + sef;
        const float s = r - 2.0f * acc[i][j];
        if (s < bv[i]) { bv[i] = s; bi[i] = cidx; }
      }
    }
  }
  __syncthreads();
  float* red_val = xs;
  int* red_idx = reinterpret_cast<int*>(xs + 128 * 17);
  const int g = wc * 8 + cgl;
#pragma unroll
  for (int i = 0; i < 8; ++i) {
    red_val[(t0 + i) * 17 + g] = bv[i];
    red_idx[(t0 + i) * 17 + g] = bi[i];
  }
  __syncthreads();
  if (tid < 128) {
    float v = red_val[tid * 17 + 0];
    int ix = red_idx[tid * 17 + 0];
#pragma unroll
    for (int gg = 1; gg < 16; ++gg) {
      const float vv = red_val[tid * 17 + gg];
      const int ii = red_idx[tid * 17 + gg];
      if (vv < v || (vv == v && ii < ix)) { v = vv; ix = ii; }
    }
    idx_out[tok0 + tid] = ix;
    idxf_out[tok0 + tid] = (float)ix;
  }
}

// ---------------- kernel 4: gather, q_st, loss partials, histogram --------
__global__ __launch_bounds__(256) void finalize_kernel(const float* __restrict__ x,
                                                       const float* __restrict__ cb,
                                                       const int* __restrict__ idx,
                                                       float* __restrict__ q_out,
                                                       unsigned int* __restrict__ counts,
                                                       double* __restrict__ partials) {
  __shared__ double tok_s[16];
  const int tid = threadIdx.x;
  const int lt = tid >> 4;
  const int ld = tid & 15;
  const int t = blockIdx.x * 16 + lt;
  const int id = idx[t];
  const float* xp = x + (size_t)t * D + ld * 16;
  const float* ep = cb + (size_t)id * D + ld * 16;
  float* qp = q_out + (size_t)t * D + ld * 16;
  float s = 0.0f;
#pragma unroll
  for (int c = 0; c < 4; ++c) {
    const float4 xv = reinterpret_cast<const float4*>(xp)[c];
    const float4 ev = reinterpret_cast<const float4*>(ep)[c];
    const float d0 = ev.x - xv.x, d1 = ev.y - xv.y;
    const float d2 = ev.z - xv.z, d3 = ev.w - xv.w;
    s = fmaf(d0, d0, s);
    s = fmaf(d1, d1, s);
    s = fmaf(d2, d2, s);
    s = fmaf(d3, d3, s);
    float4 qv;  // q_st = x + (q - x), as the reference computes it
    qv.x = xv.x + d0;
    qv.y = xv.y + d1;
    qv.z = xv.z + d2;
    qv.w = xv.w + d3;
    reinterpret_cast<float4*>(qp)[c] = qv;
  }
#pragma unroll
  for (int o = 8; o > 0; o >>= 1) s += __shfl_down(s, o, 16);
  if (ld == 0) {
    atomicAdd(&counts[id], 1u);
    tok_s[lt] = (double)s;
  }
  __syncthreads();
  if (tid == 0) {
    double bs = 0.0;
    for (int i = 0; i < 16; ++i) bs += tok_s[i];
    partials[blockIdx.x] = bs;
  }
}

// ---------------- kernel 5: scalar reductions ----------------
__global__ __launch_bounds__(256) void final_kernel(const unsigned int* __restrict__ counts,
                                                    const double* __restrict__ partials,
                                                    float* __restrict__ loss_out,
                                                    float* __restrict__ perp_out) {
  __shared__ double sh[256];
  const int tid = threadIdx.x;
  double ls = 0.0;
  for (int i = tid; i < NTOK / 16; i += 256) ls += partials[i];
  sh[tid] = ls;
  __syncthreads();
#pragma unroll
  for (int o = 128; o > 0; o >>= 1) {
    if (tid < o) sh[tid] += sh[tid + o];
    __syncthreads();
  }
  if (tid == 0) *loss_out = (float)(sh[0] * (1.25 / (256.0 * 65536.0)));
  __syncthreads();
  double hs = 0.0;
  for (int i = tid; i < KCODES; i += 256) {
    const float p = (float)counts[i] / 65536.0f;
    hs += (double)(p * logf(p + 1e-10f));
  }
  sh[tid] = hs;
  __syncthreads();
#pragma unroll
  for (int o = 128; o > 0; o >>= 1) {
    if (tid < o) sh[tid] += sh[tid + o];
    __syncthreads();
  }
  if (tid == 0) *perp_out = expf((float)(-sh[0]));
}

extern "C" void kernel_launch(void* const* d_in, const int* in_sizes, int n_in,
                              void* d_out, int out_size, void* d_ws, size_t ws_size,
                              hipStream_t stream) {
  (void)in_sizes; (void)n_in; (void)out_size;
  const float* x = (const float*)d_in[0];
  const float* cb = (const float*)d_in[1];

  float* out = (float*)d_out;
  float* q_out = out;                                  // [0, 16777216)
  float* loss_out = out + (size_t)Q_ELEMS;             // [16777216]
  float* perp_out = out + (size_t)Q_ELEMS + 1;         // [16777217]
  float* idxf_out = out + (size_t)Q_ELEMS + 2;         // [16777218, +65536)

  // ws layout (bytes):
  //   se f32[4096]           @0
  //   counts u32[4096]       @16K
  //   partials f64[4096]     @32K
  //   idx i32[65536]         @128K
  //   sx f32[65536]          @384K
  //   ovf_count u32          @640K
  //   ovf_list i32[65536]    @644K
  //   ccnt_g u32[65536]      @1M
  //   rm_g f32[65536]        @1.5M
  //   cand_g u32[65536*16]   @2M  (4MB)
  //   bpack bf16[4096*256]   @14M (2MB)
  char* ws = (char*)d_ws;
  float* se = (float*)(ws + 0);
  unsigned int* counts = (unsigned int*)(ws + (16 << 10));
  double* partials = (double*)(ws + (32 << 10));
  int* idx_i = (int*)(ws + (128 << 10));
  float* sx = (float*)(ws + (384 << 10));
  unsigned int* ovf_count = (unsigned int*)(ws + (640 << 10));
  int* ovf_list = (int*)(ws + (644 << 10));
  unsigned int* ccnt_g = (unsigned int*)(ws + (1 << 20));
  float* rm_g = (float*)(ws + (3 << 19));
  unsigned int* cand_g = (unsigned int*)(ws + (2 << 20));
  unsigned short* bpack = (unsigned short*)(ws + (14 << 20));

  hipMemsetAsync(counts, 0, KCODES * sizeof(unsigned int), stream);
  hipMemsetAsync(ovf_count, 0, sizeof(unsigned int), stream);
  ee_kernel<<<KCODES / 4, 256, 0, stream>>>(cb, se);
  xx_kernel<<<NTOK / 4, 256, 0, stream>>>(x, sx);

  if (ws_size >= (size_t)20 * 1024 * 1024) {
    pack_e_kernel<<<64, 256, 0, stream>>>(cb, bpack);
    screen4_kernel<<<NTOK / 128, 256, 0, stream>>>(x, bpack, se, ccnt_g, cand_g,
                                                   rm_g);
    rescore_kernel<<<NTOK / 256, 256, 0, stream>>>(x, cb, se, sx, ccnt_g, cand_g,
                                                   rm_g, idx_i, idxf_out,
                                                   ovf_count, ovf_list);
    ovf_kernel<<<64, 256, 0, stream>>>(x, cb, se, sx, ovf_count, ovf_list,
                                       idx_i, idxf_out);
  } else {
    argmin_fb_kernel<<<NTOK / 128, 256, 0, stream>>>(x, cb, se, sx, idx_i, idxf_out);
  }
  finalize_kernel<<<NTOK / 16, 256, 0, stream>>>(x, cb, idx_i, q_out, counts, partials);
  final_kernel<<<1, 256, 0, stream>>>(counts, partials, loss_out, perp_out);
}

// Round 11
// 365.636 us; speedup vs baseline: 1.4384x; 1.4384x over previous
//
#include <hip/hip_runtime.h>
#include <hip/hip_bf16.h>
#include <cstdint>
#include <cstddef>

#define D 256
#define NTOK 65536
#define KCODES 4096
#define Q_ELEMS (NTOK * D)   // 16777216
#define DELTA 3.0e-4f
#define CAP 24

typedef short bf16x8 __attribute__((ext_vector_type(8)));
typedef float f32x4 __attribute__((ext_vector_type(4)));
typedef unsigned short ushort8 __attribute__((ext_vector_type(8)));

__device__ __forceinline__ void gload_lds16(const float* g, float* l) {
  __builtin_amdgcn_global_load_lds(
      (const __attribute__((address_space(1))) void*)(g),
      (__attribute__((address_space(3))) void*)(l), 16, 0, 0);
}
__device__ __forceinline__ unsigned short f2bf(float f) {
  __hip_bfloat16 h = __float2bfloat16(f);
  unsigned short u;
  __builtin_memcpy(&u, &h, 2);
  return u;
}
__device__ __forceinline__ float bf2f(unsigned short u) {
  __hip_bfloat16 h;
  __builtin_memcpy(&h, &u, 2);
  return __bfloat162float(h);
}

// ---------------- kernel 1a: codebook squared norms (f64 -> f32) ----------
__global__ __launch_bounds__(256) void ee_kernel(const float* __restrict__ cb,
                                                 float* __restrict__ se) {
  const int row = blockIdx.x * 4 + (threadIdx.x >> 6);
  const int lane = threadIdx.x & 63;
  const float4 v = reinterpret_cast<const float4*>(cb + (size_t)row * D)[lane];
  double s = (double)v.x * v.x + (double)v.y * v.y +
             (double)v.z * v.z + (double)v.w * v.w;
#pragma unroll
  for (int o = 32; o > 0; o >>= 1) s += __shfl_down(s, o, 64);
  if (lane == 0) se[row] = (float)s;
}

// ---------------- kernel 1b: token squared norms (f64 -> f32) -------------
__global__ __launch_bounds__(256) void xx_kernel(const float* __restrict__ x,
                                                 float* __restrict__ sx) {
  const int row = blockIdx.x * 4 + (threadIdx.x >> 6);
  const int lane = threadIdx.x & 63;
  const float4 v = reinterpret_cast<const float4*>(x + (size_t)row * D)[lane];
  double s = (double)v.x * v.x + (double)v.y * v.y +
             (double)v.z * v.z + (double)v.w * v.w;
#pragma unroll
  for (int o = 32; o > 0; o >>= 1) s += __shfl_down(s, o, 64);
  if (lane == 0) sx[row] = (float)s;
}

// ---------------- kernel 1c: pack codebook e_hi -> LDS-image bf16 tiles ---
__global__ __launch_bounds__(256) void pack_e_kernel(const float* __restrict__ cb,
                                                     unsigned short* __restrict__ bpack) {
  const int gid = blockIdx.x * 256 + threadIdx.x;  // 16384 = 4096 codes x 4 kt
  const int c = gid >> 2;
  const int kt = gid & 3;
  const int row = c & 127;
  const int swz = (row & 7) << 3;
  unsigned short* dst = bpack + ((size_t)((c >> 7) * 4 + kt)) * 8192 + row * 64;
  const float* src = cb + (size_t)c * D + kt * 64;
#pragma unroll
  for (int j = 0; j < 8; ++j) {
    ushort8 o;
#pragma unroll
    for (int e = 0; e < 8; ++e) o[e] = f2bf(src[j * 8 + e]);
    *reinterpret_cast<ushort8*>(dst + ((j * 8) ^ swz)) = o;
  }
}

// ---------------- kernel 2: MFMA screening (r9 screen3, CAP 24) -----------
// 256 thr / 4 waves / 128 tokens per block; 512 blocks. Ring-3 bbuf (48KB),
// 2-deep prefetch, plain __syncthreads per unit; LDS 68.5KB -> 2 blocks/CU
// (r9's best-measured config, 228us). CAP 24 (r8's value): CAP 16 pushed a
// few thousand tokens into the full-scan ovf path (~+100us in r9/r10).
// d~ = se - 2*bf16(x).e_hi via mfma 16x16x32; candidates
// (bf16(score)<<16)|idx inserted when s <= running_min + DELTA.
// Capture bound: winner <= rm_final + 1.74e-4 (8sigma bf16 dot err + ref
// f32-rounding window) + 6e-5 bf16 store err < DELTA = 3e-4.
__global__ __launch_bounds__(256, 2) void screen3_kernel(
    const float* __restrict__ x, const unsigned short* __restrict__ bpack,
    const float* __restrict__ se, unsigned int* __restrict__ ccnt_g,
    unsigned int* __restrict__ cand_g, float* __restrict__ rm_g) {
  __shared__ __attribute__((aligned(16))) unsigned short bbuf[3][8192];  // 48KB
  __shared__ __attribute__((aligned(16))) unsigned short se_lds[KCODES]; // 8KB
  __shared__ unsigned int cand[128][CAP];                                // 12KB
  __shared__ unsigned int ccnt[128];                                     // 0.5KB

  const int tid = threadIdx.x;
  const int lane = tid & 63;
  const int w = tid >> 6;    // 0..3
  const int l15 = lane & 15;
  const int kg = lane >> 4;  // 0..3
  const int tok0 = blockIdx.x * 128;

  if (tid < 128) ccnt[tid] = 0;
  {  // se -> bf16 LDS: each thread converts 16 values
    const float4* s4 = reinterpret_cast<const float4*>(se) + tid * 4;
    const float4 a = s4[0], b = s4[1], c = s4[2], d = s4[3];
    ushort8 o0, o1;
    o0[0] = f2bf(a.x); o0[1] = f2bf(a.y); o0[2] = f2bf(a.z); o0[3] = f2bf(a.w);
    o0[4] = f2bf(b.x); o0[5] = f2bf(b.y); o0[6] = f2bf(b.z); o0[7] = f2bf(b.w);
    o1[0] = f2bf(c.x); o1[1] = f2bf(c.y); o1[2] = f2bf(c.z); o1[3] = f2bf(c.w);
    o1[4] = f2bf(d.x); o1[5] = f2bf(d.y); o1[6] = f2bf(d.z); o1[7] = f2bf(d.w);
    *reinterpret_cast<ushort8*>(&se_lds[tid * 16]) = o0;
    *reinterpret_cast<ushort8*>(&se_lds[tid * 16 + 8]) = o1;
  }

  // A fragments (hi-only bf16): 2 row-groups x 8 ksteps, static indices
  bf16x8 ah[2][8];
#pragma unroll
  for (int gi = 0; gi < 2; ++gi) {
    const int t = tok0 + w * 32 + gi * 16 + l15;
    const float* xp = x + (size_t)t * D;
#pragma unroll
    for (int ks = 0; ks < 8; ++ks) {
      const float4 v0 = *reinterpret_cast<const float4*>(xp + ks * 32 + kg * 8);
      const float4 v1 = *reinterpret_cast<const float4*>(xp + ks * 32 + kg * 8 + 4);
      const float xv[8] = {v0.x, v0.y, v0.z, v0.w, v1.x, v1.y, v1.z, v1.w};
      bf16x8 h;
#pragma unroll
      for (int e = 0; e < 8; ++e) h[e] = (short)f2bf(xv[e]);
      ah[gi][ks] = h;
    }
  }

  // stage one 16KB unit: 4 waves x 4 chunks x (64 lanes x 16B)
  auto STAGE = [&](int u) {
    const char* s = (const char*)bpack + (size_t)u * 16384 + w * 4096 + lane * 16;
    char* d = (char*)&bbuf[u % 3][0] + w * 4096;
    gload_lds16((const float*)s, (float*)d);
    gload_lds16((const float*)(s + 1024), (float*)(d + 1024));
    gload_lds16((const float*)(s + 2048), (float*)(d + 2048));
    gload_lds16((const float*)(s + 3072), (float*)(d + 3072));
  };

  float rm[2][4];
#pragma unroll
  for (int fr = 0; fr < 2; ++fr)
#pragma unroll
    for (int q = 0; q < 4; ++q) rm[fr][q] = 3.4e38f;

  f32x4 acc[2][8];

  STAGE(0);
  STAGE(1);
  __syncthreads();  // units 0,1 resident; se/ccnt ready

  for (int ct4 = 0; ct4 < 32; ++ct4) {
#pragma unroll
    for (int kt = 0; kt < 4; ++kt) {  // kt compile-time: ah[] stays in VGPRs
      const int u = ct4 * 4 + kt;
      if (u + 2 < 128) STAGE(u + 2);
      if (kt == 0) {
#pragma unroll
        for (int fr = 0; fr < 2; ++fr)
#pragma unroll
          for (int fc = 0; fc < 8; ++fc) acc[fr][fc] = (f32x4){0.f, 0.f, 0.f, 0.f};
      }
      const unsigned short* bb = &bbuf[u % 3][0];
#pragma unroll
      for (int kh = 0; kh < 2; ++kh) {
        const int ks = kt * 2 + kh;  // compile-time
        bf16x8 bfrag[8];
#pragma unroll
        for (int fc = 0; fc < 8; ++fc) {
          const int row = fc * 16 + l15;
          const int off = row * 64 + ((kh * 32 + kg * 8) ^ ((row & 7) << 3));
          bfrag[fc] = *reinterpret_cast<const bf16x8*>(bb + off);
        }
#pragma unroll
        for (int fr = 0; fr < 2; ++fr)
#pragma unroll
          for (int fc = 0; fc < 8; ++fc)
            acc[fr][fc] = __builtin_amdgcn_mfma_f32_16x16x32_bf16(
                ah[fr][ks], bfrag[fc], acc[fr][fc], 0, 0, 0);
      }
      if (kt == 3) {  // code-tile ct4 finished: mins + candidate inserts
        float sef[8];
#pragma unroll
        for (int fc = 0; fc < 8; ++fc)
          sef[fc] = bf2f(se_lds[ct4 * 128 + fc * 16 + l15]);
#pragma unroll
        for (int fr = 0; fr < 2; ++fr)
#pragma unroll
          for (int q = 0; q < 4; ++q) {
            float m = fmaf(-2.0f, acc[fr][0][q], sef[0]);
#pragma unroll
            for (int fc = 1; fc < 8; ++fc)
              m = fminf(m, fmaf(-2.0f, acc[fr][fc][q], sef[fc]));
            m = fminf(m, __shfl_xor(m, 1, 64));
            m = fminf(m, __shfl_xor(m, 2, 64));
            m = fminf(m, __shfl_xor(m, 4, 64));
            m = fminf(m, __shfl_xor(m, 8, 64));
            rm[fr][q] = fminf(rm[fr][q], m);
            const float thr = rm[fr][q] + DELTA;
            const int tl = w * 32 + fr * 16 + kg * 4 + q;
#pragma unroll
            for (int fc = 0; fc < 8; ++fc) {
              const float s = fmaf(-2.0f, acc[fr][fc][q], sef[fc]);
              if (s <= thr) {
                const unsigned p = atomicAdd(&ccnt[tl], 1u);
                if (p < CAP)
                  cand[tl][p] = ((unsigned)f2bf(s) << 16) |
                                (unsigned)(ct4 * 128 + fc * 16 + l15);
              }
            }
          }
      }
      __syncthreads();  // next unit resident; ring slot (u%3) free for reuse
    }
  }

  if (tid < 128) ccnt_g[tok0 + tid] = ccnt[tid];
  if (l15 == 0) {
#pragma unroll
    for (int fr = 0; fr < 2; ++fr)
#pragma unroll
      for (int q = 0; q < 4; ++q)
        rm_g[tok0 + w * 32 + fr * 16 + kg * 4 + q] = rm[fr][q];
  }
  for (int j = tid; j < 128 * CAP; j += 256)
    cand_g[(size_t)tok0 * CAP + j] = cand[j / CAP][j % CAP];
}

// ---------------- kernel 3: exact-chain rescore (filtered) ----------------
// One thread per token. Filter candidates by unpacked bf16 score <= rm+DELTA,
// then replicate reference f32 semantics bit-for-bit on the ~1-2 survivors:
// sequential fmaf chain d=0..255, dist = fl(fl(sx+se)-2*dot), lex-min.
__global__ __launch_bounds__(256) void rescore_kernel(
    const float* __restrict__ x, const float* __restrict__ cb,
    const float* __restrict__ se, const float* __restrict__ sx,
    const unsigned int* __restrict__ ccnt_g, const unsigned int* __restrict__ cand_g,
    const float* __restrict__ rm_g, int* __restrict__ idx_i,
    float* __restrict__ idxf_out, unsigned int* __restrict__ ovf_count,
    int* __restrict__ ovf_list) {
  const int t = blockIdx.x * 256 + threadIdx.x;
  const unsigned n = ccnt_g[t];
  if (n > CAP) {  // list overflowed: defer to full-scan fallback
    const unsigned p = atomicAdd(ovf_count, 1u);
    ovf_list[p] = t;
    return;
  }
  const float thr = rm_g[t] + DELTA;
  const float sxv = sx[t];
  const float4* xp = reinterpret_cast<const float4*>(x + (size_t)t * D);
  float bq = 3.4e38f;
  int bc = 0x7fffffff;
  for (unsigned k = 0; k < n; ++k) {
    const unsigned pk = cand_g[(size_t)t * CAP + k];
    if (bf2f((unsigned short)(pk >> 16)) > thr) continue;
    const int c = (int)(pk & 0xFFFFu);
    const float4* cp = reinterpret_cast<const float4*>(cb + (size_t)c * D);
    float acc = 0.0f;
#pragma unroll 8
    for (int d4 = 0; d4 < 64; ++d4) {
      const float4 xv = xp[d4];
      const float4 ev = cp[d4];
      acc = fmaf(xv.x, ev.x, acc);
      acc = fmaf(xv.y, ev.y, acc);
      acc = fmaf(xv.z, ev.z, acc);
      acc = fmaf(xv.w, ev.w, acc);
    }
    const float r = sxv + se[c];
    const float q = r - 2.0f * acc;
    if (q < bq || (q == bq && c < bc)) { bq = q; bc = c; }
  }
  idx_i[t] = bc;
  idxf_out[t] = (float)bc;
}

// ---------------- kernel 3b: full-scan fallback for overflowed tokens -----
__global__ __launch_bounds__(256) void ovf_kernel(
    const float* __restrict__ x, const float* __restrict__ cb,
    const float* __restrict__ se, const float* __restrict__ sx,
    const unsigned int* __restrict__ ovf_count, const int* __restrict__ ovf_list,
    int* __restrict__ idx_i, float* __restrict__ idxf_out) {
  __shared__ float bvv[256];
  __shared__ int bii[256];
  const int tid = threadIdx.x;
  const unsigned cnt = *ovf_count;
  for (unsigned i = blockIdx.x; i < cnt; i += gridDim.x) {
    const int t = ovf_list[i];
    const float sxv = sx[t];
    const float4* xp = reinterpret_cast<const float4*>(x + (size_t)t * D);
    float bq = 3.4e38f;
    int bc = 0x7fffffff;
    for (int c = tid; c < KCODES; c += 256) {
      const float4* cp = reinterpret_cast<const float4*>(cb + (size_t)c * D);
      float acc = 0.0f;
#pragma unroll 8
      for (int d4 = 0; d4 < 64; ++d4) {
        const float4 xv = xp[d4];
        const float4 ev = cp[d4];
        acc = fmaf(xv.x, ev.x, acc);
        acc = fmaf(xv.y, ev.y, acc);
        acc = fmaf(xv.z, ev.z, acc);
        acc = fmaf(xv.w, ev.w, acc);
      }
      const float r = sxv + se[c];
      const float q = r - 2.0f * acc;
      if (q < bq || (q == bq && c < bc)) { bq = q; bc = c; }
    }
    bvv[tid] = bq;
    bii[tid] = bc;
    __syncthreads();
    for (int o = 128; o > 0; o >>= 1) {
      if (tid < o) {
        const float v2 = bvv[tid + o];
        const int c2 = bii[tid + o];
        if (v2 < bvv[tid] || (v2 == bvv[tid] && c2 < bii[tid])) {
          bvv[tid] = v2;
          bii[tid] = c2;
        }
      }
      __syncthreads();
    }
    if (tid == 0) {
      idx_i[t] = bii[0];
      idxf_out[t] = (float)bii[0];
    }
    __syncthreads();
  }
}

// ---------------- fallback argmin (tiny-ws path; round-4 kernel) ----------
__global__ __launch_bounds__(256) void argmin_fb_kernel(const float* __restrict__ x,
                                                        const float* __restrict__ cb,
                                                        const float* __restrict__ se,
                                                        const float* __restrict__ sx,
                                                        int* __restrict__ idx_out,
                                                        float* __restrict__ idxf_out) {
  __shared__ __attribute__((aligned(16))) float xs[64 * 128];
  __shared__ __attribute__((aligned(16))) float es[64 * 128];
  const int tid = threadIdx.x;
  const int lane = tid & 63;
  const int w = tid >> 6;
  const int wt = w & 1;
  const int wc = w >> 1;
  const int tgl = lane & 7;
  const int cgl = lane >> 3;
  const int t0 = wt * 64 + tgl * 8;
  const int c0 = wc * 64 + cgl * 8;
  const int tok0 = blockIdx.x * 128;
  float sxf[8];
#pragma unroll
  for (int i = 0; i < 8; ++i) sxf[i] = sx[tok0 + t0 + i];
  float bv[8];
  int bi[8];
#pragma unroll
  for (int i = 0; i < 8; ++i) { bv[i] = 3.4e38f; bi[i] = 0; }
  for (int ct = 0; ct < KCODES / 128; ++ct) {
    float acc[8][8] = {};
    for (int kt = 0; kt < 4; ++kt) {
      __syncthreads();
      {
        const float* xsrc = x + (size_t)tok0 * D + kt * 64;
        const float* esrc = cb + (size_t)(ct * 128) * D + kt * 64;
#pragma unroll
        for (int p = 0; p < 8; ++p) {
          const int idx = p * 256 + tid;
          const int t = idx >> 4;
          const int c = idx & 15;
          const int colp = (t + 8 * (c >> 1)) & 127;
          const float4 xv = *reinterpret_cast<const float4*>(xsrc + (size_t)t * D + c * 4);
          float* xd = &xs[(c * 4) * 128 + colp];
          xd[0] = xv.x; xd[128] = xv.y; xd[256] = xv.z; xd[384] = xv.w;
          const float4 ev = *reinterpret_cast<const float4*>(esrc + (size_t)t * D + c * 4);
          float* ed = &es[(c * 4) * 128 + colp];
          ed[0] = ev.x; ed[128] = ev.y; ed[256] = ev.z; ed[384] = ev.w;
        }
      }
      __syncthreads();
      for (int kp = 0; kp < 8; ++kp) {
        const float* xb = &xs[(kp * 8) * 128 + ((t0 + 8 * kp) & 127)];
        const float* eb = &es[(kp * 8) * 128 + ((c0 + 8 * kp) & 127)];
#pragma unroll
        for (int k2 = 0; k2 < 8; ++k2) {
          const float4 xv0 = *reinterpret_cast<const float4*>(xb + k2 * 128);
          const float4 xv1 = *reinterpret_cast<const float4*>(xb + k2 * 128 + 4);
          const float4 ev0 = *reinterpret_cast<const float4*>(eb + k2 * 128);
          const float4 ev1 = *reinterpret_cast<const float4*>(eb + k2 * 128 + 4);
          const float xa[8] = {xv0.x, xv0.y, xv0.z, xv0.w, xv1.x, xv1.y, xv1.z, xv1.w};
          const float ea[8] = {ev0.x, ev0.y, ev0.z, ev0.w, ev1.x, ev1.y, ev1.z, ev1.w};
#pragma unroll
          for (int i = 0; i < 8; ++i)
#pragma unroll
            for (int j = 0; j < 8; ++j) acc[i][j] = fmaf(xa[i], ea[j], acc[i][j]);
        }
      }
    }
#pragma unroll
    for (int j = 0; j < 8; ++j) {
      const int cidx = ct * 128 + c0 + j;
      const float sef = se[cidx];
#pragma unroll
      for (int i = 0; i < 8; ++i) {
        const float r = sxf[i] + sef;
        const float s = r - 2.0f * acc[i][j];
        if (s < bv[i]) { bv[i] = s; bi[i] = cidx; }
      }
    }
  }
  __syncthreads();
  float* red_val = xs;
  int* red_idx = reinterpret_cast<int*>(xs + 128 * 17);
  const int g = wc * 8 + cgl;
#pragma unroll
  for (int i = 0; i < 8; ++i) {
    red_val[(t0 + i) * 17 + g] = bv[i];
    red_idx[(t0 + i) * 17 + g] = bi[i];
  }
  __syncthreads();
  if (tid < 128) {
    float v = red_val[tid * 17 + 0];
    int ix = red_idx[tid * 17 + 0];
#pragma unroll
    for (int gg = 1; gg < 16; ++gg) {
      const float vv = red_val[tid * 17 + gg];
      const int ii = red_idx[tid * 17 + gg];
      if (vv < v || (vv == v && ii < ix)) { v = vv; ix = ii; }
    }
    idx_out[tok0 + tid] = ix;
    idxf_out[tok0 + tid] = (float)ix;
  }
}

// ---------------- kernel 4: gather, q_st, loss partials, histogram --------
__global__ __launch_bounds__(256) void finalize_kernel(const float* __restrict__ x,
                                                       const float* __restrict__ cb,
                                                       const int* __restrict__ idx,
                                                       float* __restrict__ q_out,
                                                       unsigned int* __restrict__ counts,
                                                       double* __restrict__ partials) {
  __shared__ double tok_s[16];
  const int tid = threadIdx.x;
  const int lt = tid >> 4;
  const int ld = tid & 15;
  const int t = blockIdx.x * 16 + lt;
  const int id = idx[t];
  const float* xp = x + (size_t)t * D + ld * 16;
  const float* ep = cb + (size_t)id * D + ld * 16;
  float* qp = q_out + (size_t)t * D + ld * 16;
  float s = 0.0f;
#pragma unroll
  for (int c = 0; c < 4; ++c) {
    const float4 xv = reinterpret_cast<const float4*>(xp)[c];
    const float4 ev = reinterpret_cast<const float4*>(ep)[c];
    const float d0 = ev.x - xv.x, d1 = ev.y - xv.y;
    const float d2 = ev.z - xv.z, d3 = ev.w - xv.w;
    s = fmaf(d0, d0, s);
    s = fmaf(d1, d1, s);
    s = fmaf(d2, d2, s);
    s = fmaf(d3, d3, s);
    float4 qv;  // q_st = x + (q - x), as the reference computes it
    qv.x = xv.x + d0;
    qv.y = xv.y + d1;
    qv.z = xv.z + d2;
    qv.w = xv.w + d3;
    reinterpret_cast<float4*>(qp)[c] = qv;
  }
#pragma unroll
  for (int o = 8; o > 0; o >>= 1) s += __shfl_down(s, o, 16);
  if (ld == 0) {
    atomicAdd(&counts[id], 1u);
    tok_s[lt] = (double)s;
  }
  __syncthreads();
  if (tid == 0) {
    double bs = 0.0;
    for (int i = 0; i < 16; ++i) bs += tok_s[i];
    partials[blockIdx.x] = bs;
  }
}

// ---------------- kernel 5: scalar reductions ----------------
__global__ __launch_bounds__(256) void final_kernel(const unsigned int* __restrict__ counts,
                                                    const double* __restrict__ partials,
                                                    float* __restrict__ loss_out,
                                                    float* __restrict__ perp_out) {
  __shared__ double sh[256];
  const int tid = threadIdx.x;
  double ls = 0.0;
  for (int i = tid; i < NTOK / 16; i += 256) ls += partials[i];
  sh[tid] = ls;
  __syncthreads();
#pragma unroll
  for (int o = 128; o > 0; o >>= 1) {
    if (tid < o) sh[tid] += sh[tid + o];
    __syncthreads();
  }
  if (tid == 0) *loss_out = (float)(sh[0] * (1.25 / (256.0 * 65536.0)));
  __syncthreads();
  double hs = 0.0;
  for (int i = tid; i < KCODES; i += 256) {
    const float p = (float)counts[i] / 65536.0f;
    hs += (double)(p * logf(p + 1e-10f));
  }
  sh[tid] = hs;
  __syncthreads();
#pragma unroll
  for (int o = 128; o > 0; o >>= 1) {
    if (tid < o) sh[tid] += sh[tid + o];
    __syncthreads();
  }
  if (tid == 0) *perp_out = expf((float)(-sh[0]));
}

extern "C" void kernel_launch(void* const* d_in, const int* in_sizes, int n_in,
                              void* d_out, int out_size, void* d_ws, size_t ws_size,
                              hipStream_t stream) {
  (void)in_sizes; (void)n_in; (void)out_size;
  const float* x = (const float*)d_in[0];
  const float* cb = (const float*)d_in[1];

  float* out = (float*)d_out;
  float* q_out = out;                                  // [0, 16777216)
  float* loss_out = out + (size_t)Q_ELEMS;             // [16777216]
  float* perp_out = out + (size_t)Q_ELEMS + 1;         // [16777217]
  float* idxf_out = out + (size_t)Q_ELEMS + 2;         // [16777218, +65536)

  // ws layout (bytes):
  //   se f32[4096]           @0
  //   counts u32[4096]       @16K
  //   partials f64[4096]     @32K
  //   idx i32[65536]         @128K
  //   sx f32[65536]          @384K
  //   ovf_count u32          @640K
  //   ovf_list i32[65536]    @644K
  //   ccnt_g u32[65536]      @1M
  //   rm_g f32[65536]        @1.5M
  //   cand_g u32[65536*24]   @2M  (6MB)
  //   bpack bf16[4096*256]   @14M (2MB)
  char* ws = (char*)d_ws;
  float* se = (float*)(ws + 0);
  unsigned int* counts = (unsigned int*)(ws + (16 << 10));
  double* partials = (double*)(ws + (32 << 10));
  int* idx_i = (int*)(ws + (128 << 10));
  float* sx = (float*)(ws + (384 << 10));
  unsigned int* ovf_count = (unsigned int*)(ws + (640 << 10));
  int* ovf_list = (int*)(ws + (644 << 10));
  unsigned int* ccnt_g = (unsigned int*)(ws + (1 << 20));
  float* rm_g = (float*)(ws + (3 << 19));
  unsigned int* cand_g = (unsigned int*)(ws + (2 << 20));
  unsigned short* bpack = (unsigned short*)(ws + (14 << 20));

  hipMemsetAsync(counts, 0, KCODES * sizeof(unsigned int), stream);
  hipMemsetAsync(ovf_count, 0, sizeof(unsigned int), stream);
  ee_kernel<<<KCODES / 4, 256, 0, stream>>>(cb, se);
  xx_kernel<<<NTOK / 4, 256, 0, stream>>>(x, sx);

  if (ws_size >= (size_t)20 * 1024 * 1024) {
    pack_e_kernel<<<64, 256, 0, stream>>>(cb, bpack);
    screen3_kernel<<<NTOK / 128, 256, 0, stream>>>(x, bpack, se, ccnt_g, cand_g,
                                                   rm_g);
    rescore_kernel<<<NTOK / 256, 256, 0, stream>>>(x, cb, se, sx, ccnt_g, cand_g,
                                                   rm_g, idx_i, idxf_out,
                                                   ovf_count, ovf_list);
    ovf_kernel<<<64, 256, 0, stream>>>(x, cb, se, sx, ovf_count, ovf_list,
                                       idx_i, idxf_out);
  } else {
    argmin_fb_kernel<<<NTOK / 128, 256, 0, stream>>>(x, cb, se, sx, idx_i, idxf_out);
  }
  finalize_kernel<<<NTOK / 16, 256, 0, stream>>>(x, cb, idx_i, q_out, counts, partials);
  final_kernel<<<1, 256, 0, stream>>>(counts, partials, loss_out, perp_out);
}